// Round 6
// baseline (398.393 us; speedup 1.0000x reference)
//
#include <hip/hip_runtime.h>

#define C 10
#define CHUNK_ROWS 128
#define CHUNK_FLOATS 1280   // 128 rows * 10
#define CHUNK_F4 320        // float4s per chunk

typedef float f4_t __attribute__((ext_vector_type(4)));
typedef float f2_t __attribute__((ext_vector_type(2)));

__device__ __forceinline__ float waveSum(float v) {
#pragma unroll
  for (int o = 32; o > 0; o >>= 1) v += __shfl_down(v, o, 64);
  return v;
}
__device__ __forceinline__ float waveMin(float v) {
#pragma unroll
  for (int o = 32; o > 0; o >>= 1) v = fminf(v, __shfl_down(v, o, 64));
  return v;
}
__device__ __forceinline__ float waveMax(float v) {
#pragma unroll
  for (int o = 32; o > 0; o >>= 1) v = fmaxf(v, __shfl_down(v, o, 64));
  return v;
}
__device__ __forceinline__ unsigned waveMaxU(unsigned v) {
#pragma unroll
  for (int o = 32; o > 0; o >>= 1) {
    unsigned w = (unsigned)__shfl_down((int)v, o, 64);
    v = v > w ? v : w;
  }
  return v;
}

// NT loads for one chunk into a NAMED register set (static indices only).
__device__ __forceinline__ void issueChunk(const f4_t* __restrict__ bp,
                                           const f4_t* __restrict__ by, int c,
                                           int lane, f4_t (&P)[5], f4_t (&Y)[5]) {
  const f4_t* gp = bp + (size_t)c * CHUNK_F4 + lane;
  const f4_t* gy = by + (size_t)c * CHUNK_F4 + lane;
#pragma unroll
  for (int q = 0; q < 5; ++q) {
    P[q] = __builtin_nontemporal_load(gp + q * 64);
    Y[q] = __builtin_nontemporal_load(gy + q * 64);
  }
}

// Elementwise phase: ce/focal partials + stage p into this wave's LDS slice.
__device__ __forceinline__ void elemwise(const f4_t (&P)[5], const f4_t (&Y)[5],
                                         f4_t* __restrict__ bufP, int lane,
                                         float& ceA, float& foA) {
#pragma unroll
  for (int q = 0; q < 5; ++q) {
    f4_t pv = P[q], yv = Y[q];
    float lpx = __logf(fmaxf(pv.x, 1e-10f));
    float lpy = __logf(fmaxf(pv.y, 1e-10f));
    float lpz = __logf(fmaxf(pv.z, 1e-10f));
    float lpw = __logf(fmaxf(pv.w, 1e-10f));
    // lp8 = log(max(p,1e-8)) == max(lp, log(1e-8))
    float tx = yv.x * fmaxf(lpx, -18.420681f);
    float ty = yv.y * fmaxf(lpy, -18.420681f);
    float tz = yv.z * fmaxf(lpz, -18.420681f);
    float tw = yv.w * fmaxf(lpw, -18.420681f);
    ceA -= tx + ty + tz + tw;
    foA -= tx * (1.f - pv.x) + ty * (1.f - pv.y) + tz * (1.f - pv.z) +
           tw * (1.f - pv.w);
    bufP[q * 64 + lane] = pv;
  }
}

// ---------------- pass 1: NT-streamed (round-4 A/B: NT loads beat plain/L3
// by ~35us despite forfeiting L3 hits), now with DEPTH-2 register prefetch:
// two named P/Y sets; each chunk's loads are issued one full chunk-processing
// span ahead (elementwise+row of the other buffer), not just the row phase.
// ~96-112 VGPR, under the (128,4) cap of 128 -> no forced spill (round-1's
// disaster was the cap at 32, not prefetch). LDS 10240 B/block.
__global__ __launch_bounds__(128, 4) void pass1(
    const float4* __restrict__ probs4, const float4* __restrict__ y4,
    float2* __restrict__ us2,
    unsigned* __restrict__ uminInvSlots, unsigned* __restrict__ umaxSlots,
    float* __restrict__ ceSlots, float* __restrict__ focalSlots,
    int nchunks) {
  __shared__ float lds[2 * CHUNK_FLOATS];  // [wave][p: 320 f4] = 10240 B
  const int widx = threadIdx.x >> 6, lane = threadIdx.x & 63;
  f4_t* const bufP = (f4_t*)(lds + widx * CHUNK_FLOATS);
  const f4_t* bp = (const f4_t*)probs4;
  const f4_t* by = (const f4_t*)y4;

  const int gw = blockIdx.x * 2 + widx;  // global wave id
  const int NW = gridDim.x * 2;

  // label0 = argmax of flattened y == label of sample 0 (first max). L2-hot.
  int label0 = 0;
  {
    const float* yf = (const float*)y4;
    float m = yf[0];
#pragma unroll
    for (int c = 1; c < C; ++c) {
      float v = yf[c];
      if (v > m) { m = v; label0 = c; }
    }
  }

  float ceA = 0.f, foA = 0.f;
  float mnA = __uint_as_float(0x7f800000u), mxA = 0.f;

  // Row phase on the wave's LDS slice (wave-synchronous, no barriers).
  auto rowphase = [&](int c) {
    float u0 = 0.f, u1 = 0.f;
    float m0 = -1.f, m1 = -1.f;
    int am0 = 0, am1 = 0;
#pragma unroll
    for (int q = 0; q < 5; ++q) {
      f4_t v = bufP[lane * 5 + q];
      float vv[4] = {v.x, v.y, v.z, v.w};
#pragma unroll
      for (int j = 0; j < 4; ++j) {
        int e = 4 * q + j;  // compile-time after unroll
        float p = vv[j];
        float lp = __logf(fmaxf(p, 1e-10f));
        if (e < 10) {
          u0 -= p * lp;
          if (p > m0) { m0 = p; am0 = e; }      // strict > keeps first max
        } else {
          u1 -= p * lp;
          if (p > m1) { m1 = p; am1 = e - 10; }
        }
      }
    }
    mnA = fminf(mnA, fminf(u0, u1));
    mxA = fmaxf(mxA, fmaxf(u0, u1));
    // pack acc into sign bit (unc >= 0; sign set == inaccurate)
    unsigned s0 = __float_as_uint(u0) | ((am0 == label0) ? 0u : 0x80000000u);
    unsigned s1 = __float_as_uint(u1) | ((am1 == label0) ? 0u : 0x80000000u);
    f2_t o;
    o.x = __uint_as_float(s0);
    o.y = __uint_as_float(s1);
    __builtin_nontemporal_store(o, (f2_t*)&us2[(size_t)c * 64 + lane]);
  };

  f4_t PA[5], YA[5], PB[5], YB[5];
  if (gw < nchunks) issueChunk(bp, by, gw, lane, PA, YA);
  if (gw + NW < nchunks) issueChunk(bp, by, gw + NW, lane, PB, YB);

  for (int c = gw; c < nchunks; c += 2 * NW) {
    // ---- chunk c from buffer A
    elemwise(PA, YA, bufP, lane, ceA, foA);
    if (c + 2 * NW < nchunks) issueChunk(bp, by, c + 2 * NW, lane, PA, YA);
    rowphase(c);

    // ---- chunk c+NW from buffer B
    int c2 = c + NW;
    if (c2 < nchunks) {
      elemwise(PB, YB, bufP, lane, ceA, foA);
      if (c2 + 2 * NW < nchunks) issueChunk(bp, by, c2 + 2 * NW, lane, PB, YB);
      rowphase(c2);
    }
  }

  // per-wave reduce + spread-slot atomics.
  float ce = waveSum(ceA), fo = waveSum(foA);
  float mn = waveMin(mnA), mx = waveMax(mxA);
  if (lane == 0) {
    int slot = gw & 63;
    atomicAdd(&ceSlots[slot], ce);
    atomicAdd(&focalSlots[slot], fo);
    atomicMax(&uminInvSlots[slot], ~__float_as_uint(mn));  // min via ~bits
    atomicMax(&umaxSlots[slot], __float_as_uint(mx));
  }
}

// ---------------- pass 2: 22-bin x 4-category histogram. grid 1024 = exactly
// 4 iterations/thread. NO done-counter / fused finale (round-3 regression:
// same-address cross-XCD atomics + serial agent loads). NT load on us.
__global__ __launch_bounds__(256, 4) void pass2(
    const float4* __restrict__ us4, int n4,
    const unsigned* __restrict__ uminInvSlots, const unsigned* __restrict__ umaxSlots,
    float* __restrict__ ghist) {
  __shared__ float hist[88 * 64];  // [row][lane], 22528 B
  __shared__ float smm[2];
  const int tid = threadIdx.x, lane = tid & 63;
  for (int i = tid; i < 88 * 64; i += 256) hist[i] = 0.f;
  if (tid < 64) {
    unsigned mnInv = waveMaxU(uminInvSlots[tid]);
    unsigned mxb = waveMaxU(umaxSlots[tid]);
    if (tid == 0) { smm[0] = __uint_as_float(~mnInv); smm[1] = __uint_as_float(mxb); }
  }
  __syncthreads();
  const float umin = smm[0], delta = smm[1] - smm[0];
  float th[21];
#pragma unroll
  for (int k = 0; k < 21; ++k) th[k] = fmaf(0.05f * (float)k, delta, umin);

  const int stride = gridDim.x * 256;
  for (int i = blockIdx.x * 256 + tid; i < n4; i += stride) {
    f4_t v = __builtin_nontemporal_load((const f4_t*)us4 + i);
    float vv[4] = {v.x, v.y, v.z, v.w};
#pragma unroll
    for (int q = 0; q < 4; ++q) {
      unsigned b = __float_as_uint(vv[q]);
      int rb = (b >> 31) ? 44 : 0;  // acc rows 0..43, inacc rows 44..87
      float u = __uint_as_float(b & 0x7fffffffu);
      float e = u * 0.4342944819f;  // u / ln(10)
      float lnum = __logf(e * 0.9f);
      float lden = __logf(fmaxf((1.f - e) * 0.1f, 1e-10f));
      float x = fmaxf(lnum - lden, -23.0258509f) * 100.f;
      float s = __builtin_amdgcn_rcpf(1.f + __expf(-x));                   // sigmoid
      float t = 1.f - 2.f * __builtin_amdgcn_rcpf(__expf(2.f * u) + 1.f);  // tanh
      float wc = (1.f - s) * (1.f - t), wu = s * t;
      int j = 0;  // j = #{k: u > th_k}; le[k] <=> k >= j
#pragma unroll
      for (int k = 0; k < 21; ++k) j += (u > th[k]) ? 1 : 0;
      atomicAdd(&hist[(rb + j) * 64 + lane], wc);        // ds_add_f32
      atomicAdd(&hist[(rb + 22 + j) * 64 + lane], wu);
    }
  }
  __syncthreads();
  // tree-reduce 64 columns per row
#pragma unroll
  for (int st = 32; st >= 1; st >>= 1) {
    for (int idx = tid; idx < 88 * st; idx += 256) {
      int r = idx / st, c = idx - r * st;
      hist[r * 64 + c] += hist[r * 64 + c + st];
    }
    __syncthreads();
  }
  int slot = blockIdx.x & 63;
  for (int r = tid; r < 88; r += 256)
    atomicAdd(&ghist[slot * 88 + r], hist[r * 64]);
}

// ---------------- pass 3: reduce 64 slot-copies + scalar slots, emit outputs
__global__ __launch_bounds__(256) void pass3(
    const float* __restrict__ ghist,
    const float* __restrict__ ceSlots, const float* __restrict__ focalSlots,
    float* __restrict__ out, float invN) {
  __shared__ float hr[96];
  __shared__ float scf[2];
  int tid = threadIdx.x;
  if (tid < 88) {
    float s = 0.f;
    for (int q = 0; q < 64; ++q) s += ghist[q * 88 + tid];  // coalesced across tid
    hr[tid] = s;
  }
  if (tid >= 128 && tid < 192) {
    int l = tid - 128;
    float ce = waveSum(ceSlots[l]);
    float fo = waveSum(focalSlots[l]);
    if (l == 0) { scf[0] = ce; scf[1] = fo; }
  }
  __syncthreads();
  if (tid == 0) {
    // Running sums straight from LDS (low-VGPR finale).
    float totAU = 0.f, totIU = 0.f;
    for (int j = 0; j < 22; ++j) { totAU += hr[22 + j]; totIU += hr[66 + j]; }
    float n_ac = 0.f, n_ic = 0.f, n_au = totAU, n_iu = totIU;
    float auc = 0.f, prev = 0.f;
    for (int k = 0; k < 21; ++k) {
      n_ac += hr[k]; n_ic += hr[44 + k];
      n_au -= hr[22 + k]; n_iu -= hr[66 + k];
      float avu = (n_ac + n_iu) / (n_ac + n_au + n_ic + n_iu + 1e-10f);
      if (k > 0) auc += (avu + prev) * 0.5f * 0.05f;
      prev = avu;
    }
    out[0] = -logf(fmaxf(auc, 1e-10f)) + scf[1] * invN;
    out[1] = scf[0] * invN;
  }
}

extern "C" void kernel_launch(void* const* d_in, const int* in_sizes, int n_in,
                              void* d_out, int out_size, void* d_ws, size_t ws_size,
                              hipStream_t stream) {
  const float* probs = (const float*)d_in[0];
  const float* y = (const float*)d_in[1];
  float* out = (float*)d_out;
  const int N = in_sizes[0] / C;

  // ws layout (floats): [0,64) uminInv slots, [64,128) umax slots,
  // [128,192) ce slots, [192,256) focal slots, [256,5888) ghist[64][88],
  // [5888, 5888+N) us
  float* wsf = (float*)d_ws;
  unsigned* uminInvSlots = (unsigned*)wsf;
  unsigned* umaxSlots = (unsigned*)(wsf + 64);
  float* ceSlots = wsf + 128;
  float* focalSlots = wsf + 192;
  float* ghist = wsf + 256;
  float* us = wsf + 5888;

  hipMemsetAsync(d_ws, 0, 5888 * sizeof(float), stream);  // accumulators -> 0

  const int nchunks = N / CHUNK_ROWS;  // 4194304/128 = 32768
  float invN = 1.0f / (float)N;

  pass1<<<4096, 128, 0, stream>>>((const float4*)probs, (const float4*)y,
                                  (float2*)us, uminInvSlots, umaxSlots,
                                  ceSlots, focalSlots, nchunks);
  pass2<<<1024, 256, 0, stream>>>((const float4*)us, N / 4, uminInvSlots,
                                  umaxSlots, ghist);
  pass3<<<1, 256, 0, stream>>>(ghist, ceSlots, focalSlots, out, invN);
}

// Round 7
// 376.530 us; speedup vs baseline: 1.0581x; 1.0581x over previous
//
#include <hip/hip_runtime.h>

#define C 10
#define CHUNK_ROWS 128
#define CHUNK_FLOATS 1280   // 128 rows * 10
#define CHUNK_F4 320        // float4s per chunk

typedef float f4_t __attribute__((ext_vector_type(4)));
typedef float f2_t __attribute__((ext_vector_type(2)));

__device__ __forceinline__ float waveSum(float v) {
#pragma unroll
  for (int o = 32; o > 0; o >>= 1) v += __shfl_down(v, o, 64);
  return v;
}
__device__ __forceinline__ float waveMin(float v) {
#pragma unroll
  for (int o = 32; o > 0; o >>= 1) v = fminf(v, __shfl_down(v, o, 64));
  return v;
}
__device__ __forceinline__ float waveMax(float v) {
#pragma unroll
  for (int o = 32; o > 0; o >>= 1) v = fmaxf(v, __shfl_down(v, o, 64));
  return v;
}
__device__ __forceinline__ unsigned waveMaxU(unsigned v) {
#pragma unroll
  for (int o = 32; o > 0; o >>= 1) {
    unsigned w = (unsigned)__shfl_down((int)v, o, 64);
    v = v > w ? v : w;
  }
  return v;
}

// NT loads for one chunk into a NAMED register set (static indices only).
__device__ __forceinline__ void issueChunk(const f4_t* __restrict__ bp,
                                           const f4_t* __restrict__ by, int c,
                                           int lane, f4_t (&P)[5], f4_t (&Y)[5]) {
  const f4_t* gp = bp + (size_t)c * CHUNK_F4 + lane;
  const f4_t* gy = by + (size_t)c * CHUNK_F4 + lane;
#pragma unroll
  for (int q = 0; q < 5; ++q) {
    P[q] = __builtin_nontemporal_load(gp + q * 64);
    Y[q] = __builtin_nontemporal_load(gy + q * 64);
  }
}

// Elementwise phase: ce/focal partials + stage p into this wave's LDS slice.
__device__ __forceinline__ void elemwise(const f4_t (&P)[5], const f4_t (&Y)[5],
                                         f4_t* __restrict__ bufP, int lane,
                                         float& ceA, float& foA) {
#pragma unroll
  for (int q = 0; q < 5; ++q) {
    f4_t pv = P[q], yv = Y[q];
    float lpx = __logf(fmaxf(pv.x, 1e-10f));
    float lpy = __logf(fmaxf(pv.y, 1e-10f));
    float lpz = __logf(fmaxf(pv.z, 1e-10f));
    float lpw = __logf(fmaxf(pv.w, 1e-10f));
    // lp8 = log(max(p,1e-8)) == max(lp, log(1e-8))
    float tx = yv.x * fmaxf(lpx, -18.420681f);
    float ty = yv.y * fmaxf(lpy, -18.420681f);
    float tz = yv.z * fmaxf(lpz, -18.420681f);
    float tw = yv.w * fmaxf(lpw, -18.420681f);
    ceA -= tx + ty + tz + tw;
    foA -= tx * (1.f - pv.x) + ty * (1.f - pv.y) + tz * (1.f - pv.z) +
           tw * (1.f - pv.w);
    bufP[q * 64 + lane] = pv;
  }
}

// ---------------- pass 1: NT-streamed (round-4/5 A/B: NT loads beat plain/L3
// by ~35us despite forfeiting L3 hits) with DEPTH-2 register prefetch.
// ROUND-6 LESSON: under __launch_bounds__(128,4) the allocator targeted 64
// VGPR and SPILLED the second buffer set (WRITE_SIZE 17->85MB, no win).
// (128,2) raises the allocator ceiling to 256 so the ~110 live regs fit;
// worst case 4 waves/SIMD = 16 waves/CU, same as round-4's measured
// occupancy. GATE: WRITE_SIZE must be ~17MB (clean) or this reverts.
__global__ __launch_bounds__(128, 2) void pass1(
    const float4* __restrict__ probs4, const float4* __restrict__ y4,
    float2* __restrict__ us2,
    unsigned* __restrict__ uminInvSlots, unsigned* __restrict__ umaxSlots,
    float* __restrict__ ceSlots, float* __restrict__ focalSlots,
    int nchunks) {
  __shared__ float lds[2 * CHUNK_FLOATS];  // [wave][p: 320 f4] = 10240 B
  const int widx = threadIdx.x >> 6, lane = threadIdx.x & 63;
  f4_t* const bufP = (f4_t*)(lds + widx * CHUNK_FLOATS);
  const f4_t* bp = (const f4_t*)probs4;
  const f4_t* by = (const f4_t*)y4;

  const int gw = blockIdx.x * 2 + widx;  // global wave id
  const int NW = gridDim.x * 2;

  // label0 = argmax of flattened y == label of sample 0 (first max). L2-hot.
  int label0 = 0;
  {
    const float* yf = (const float*)y4;
    float m = yf[0];
#pragma unroll
    for (int c = 1; c < C; ++c) {
      float v = yf[c];
      if (v > m) { m = v; label0 = c; }
    }
  }

  float ceA = 0.f, foA = 0.f;
  float mnA = __uint_as_float(0x7f800000u), mxA = 0.f;

  // Row phase on the wave's LDS slice (wave-synchronous, no barriers).
  auto rowphase = [&](int c) {
    float u0 = 0.f, u1 = 0.f;
    float m0 = -1.f, m1 = -1.f;
    int am0 = 0, am1 = 0;
#pragma unroll
    for (int q = 0; q < 5; ++q) {
      f4_t v = bufP[lane * 5 + q];
      float vv[4] = {v.x, v.y, v.z, v.w};
#pragma unroll
      for (int j = 0; j < 4; ++j) {
        int e = 4 * q + j;  // compile-time after unroll
        float p = vv[j];
        float lp = __logf(fmaxf(p, 1e-10f));
        if (e < 10) {
          u0 -= p * lp;
          if (p > m0) { m0 = p; am0 = e; }      // strict > keeps first max
        } else {
          u1 -= p * lp;
          if (p > m1) { m1 = p; am1 = e - 10; }
        }
      }
    }
    mnA = fminf(mnA, fminf(u0, u1));
    mxA = fmaxf(mxA, fmaxf(u0, u1));
    // pack acc into sign bit (unc >= 0; sign set == inaccurate)
    unsigned s0 = __float_as_uint(u0) | ((am0 == label0) ? 0u : 0x80000000u);
    unsigned s1 = __float_as_uint(u1) | ((am1 == label0) ? 0u : 0x80000000u);
    f2_t o;
    o.x = __uint_as_float(s0);
    o.y = __uint_as_float(s1);
    __builtin_nontemporal_store(o, (f2_t*)&us2[(size_t)c * 64 + lane]);
  };

  f4_t PA[5], YA[5], PB[5], YB[5];
  if (gw < nchunks) issueChunk(bp, by, gw, lane, PA, YA);
  if (gw + NW < nchunks) issueChunk(bp, by, gw + NW, lane, PB, YB);

  for (int c = gw; c < nchunks; c += 2 * NW) {
    // ---- chunk c from buffer A (its loads have been in flight for a full
    // chunk-processing span; B's loads remain in flight through this body)
    elemwise(PA, YA, bufP, lane, ceA, foA);
    if (c + 2 * NW < nchunks) issueChunk(bp, by, c + 2 * NW, lane, PA, YA);
    rowphase(c);

    // ---- chunk c+NW from buffer B
    int c2 = c + NW;
    if (c2 < nchunks) {
      elemwise(PB, YB, bufP, lane, ceA, foA);
      if (c2 + 2 * NW < nchunks) issueChunk(bp, by, c2 + 2 * NW, lane, PB, YB);
      rowphase(c2);
    }
  }

  // per-wave reduce + spread-slot atomics.
  float ce = waveSum(ceA), fo = waveSum(foA);
  float mn = waveMin(mnA), mx = waveMax(mxA);
  if (lane == 0) {
    int slot = gw & 63;
    atomicAdd(&ceSlots[slot], ce);
    atomicAdd(&focalSlots[slot], fo);
    atomicMax(&uminInvSlots[slot], ~__float_as_uint(mn));  // min via ~bits
    atomicMax(&umaxSlots[slot], __float_as_uint(mx));
  }
}

// ---------------- pass 2: 22-bin x 4-category histogram. grid 1024 = exactly
// 4 iterations/thread. NO done-counter / fused finale (round-3 regression:
// ~128us of serialized same-address cross-XCD atomics). NT load on us.
__global__ __launch_bounds__(256, 4) void pass2(
    const float4* __restrict__ us4, int n4,
    const unsigned* __restrict__ uminInvSlots, const unsigned* __restrict__ umaxSlots,
    float* __restrict__ ghist) {
  __shared__ float hist[88 * 64];  // [row][lane], 22528 B
  __shared__ float smm[2];
  const int tid = threadIdx.x, lane = tid & 63;
  for (int i = tid; i < 88 * 64; i += 256) hist[i] = 0.f;
  if (tid < 64) {
    unsigned mnInv = waveMaxU(uminInvSlots[tid]);
    unsigned mxb = waveMaxU(umaxSlots[tid]);
    if (tid == 0) { smm[0] = __uint_as_float(~mnInv); smm[1] = __uint_as_float(mxb); }
  }
  __syncthreads();
  const float umin = smm[0], delta = smm[1] - smm[0];
  float th[21];
#pragma unroll
  for (int k = 0; k < 21; ++k) th[k] = fmaf(0.05f * (float)k, delta, umin);

  const int stride = gridDim.x * 256;
  for (int i = blockIdx.x * 256 + tid; i < n4; i += stride) {
    f4_t v = __builtin_nontemporal_load((const f4_t*)us4 + i);
    float vv[4] = {v.x, v.y, v.z, v.w};
#pragma unroll
    for (int q = 0; q < 4; ++q) {
      unsigned b = __float_as_uint(vv[q]);
      int rb = (b >> 31) ? 44 : 0;  // acc rows 0..43, inacc rows 44..87
      float u = __uint_as_float(b & 0x7fffffffu);
      float e = u * 0.4342944819f;  // u / ln(10)
      float lnum = __logf(e * 0.9f);
      float lden = __logf(fmaxf((1.f - e) * 0.1f, 1e-10f));
      float x = fmaxf(lnum - lden, -23.0258509f) * 100.f;
      float s = __builtin_amdgcn_rcpf(1.f + __expf(-x));                   // sigmoid
      float t = 1.f - 2.f * __builtin_amdgcn_rcpf(__expf(2.f * u) + 1.f);  // tanh
      float wc = (1.f - s) * (1.f - t), wu = s * t;
      int j = 0;  // j = #{k: u > th_k}; le[k] <=> k >= j
#pragma unroll
      for (int k = 0; k < 21; ++k) j += (u > th[k]) ? 1 : 0;
      atomicAdd(&hist[(rb + j) * 64 + lane], wc);        // ds_add_f32
      atomicAdd(&hist[(rb + 22 + j) * 64 + lane], wu);
    }
  }
  __syncthreads();
  // tree-reduce 64 columns per row
#pragma unroll
  for (int st = 32; st >= 1; st >>= 1) {
    for (int idx = tid; idx < 88 * st; idx += 256) {
      int r = idx / st, c = idx - r * st;
      hist[r * 64 + c] += hist[r * 64 + c + st];
    }
    __syncthreads();
  }
  int slot = blockIdx.x & 63;
  for (int r = tid; r < 88; r += 256)
    atomicAdd(&ghist[slot * 88 + r], hist[r * 64]);
}

// ---------------- pass 3: reduce 64 slot-copies + scalar slots, emit outputs
__global__ __launch_bounds__(256) void pass3(
    const float* __restrict__ ghist,
    const float* __restrict__ ceSlots, const float* __restrict__ focalSlots,
    float* __restrict__ out, float invN) {
  __shared__ float hr[96];
  __shared__ float scf[2];
  int tid = threadIdx.x;
  if (tid < 88) {
    float s = 0.f;
    for (int q = 0; q < 64; ++q) s += ghist[q * 88 + tid];  // coalesced across tid
    hr[tid] = s;
  }
  if (tid >= 128 && tid < 192) {
    int l = tid - 128;
    float ce = waveSum(ceSlots[l]);
    float fo = waveSum(focalSlots[l]);
    if (l == 0) { scf[0] = ce; scf[1] = fo; }
  }
  __syncthreads();
  if (tid == 0) {
    // Running sums straight from LDS (low-VGPR finale).
    float totAU = 0.f, totIU = 0.f;
    for (int j = 0; j < 22; ++j) { totAU += hr[22 + j]; totIU += hr[66 + j]; }
    float n_ac = 0.f, n_ic = 0.f, n_au = totAU, n_iu = totIU;
    float auc = 0.f, prev = 0.f;
    for (int k = 0; k < 21; ++k) {
      n_ac += hr[k]; n_ic += hr[44 + k];
      n_au -= hr[22 + k]; n_iu -= hr[66 + k];
      float avu = (n_ac + n_iu) / (n_ac + n_au + n_ic + n_iu + 1e-10f);
      if (k > 0) auc += (avu + prev) * 0.5f * 0.05f;
      prev = avu;
    }
    out[0] = -logf(fmaxf(auc, 1e-10f)) + scf[1] * invN;
    out[1] = scf[0] * invN;
  }
}

extern "C" void kernel_launch(void* const* d_in, const int* in_sizes, int n_in,
                              void* d_out, int out_size, void* d_ws, size_t ws_size,
                              hipStream_t stream) {
  const float* probs = (const float*)d_in[0];
  const float* y = (const float*)d_in[1];
  float* out = (float*)d_out;
  const int N = in_sizes[0] / C;

  // ws layout (floats): [0,64) uminInv slots, [64,128) umax slots,
  // [128,192) ce slots, [192,256) focal slots, [256,5888) ghist[64][88],
  // [5888, 5888+N) us
  float* wsf = (float*)d_ws;
  unsigned* uminInvSlots = (unsigned*)wsf;
  unsigned* umaxSlots = (unsigned*)(wsf + 64);
  float* ceSlots = wsf + 128;
  float* focalSlots = wsf + 192;
  float* ghist = wsf + 256;
  float* us = wsf + 5888;

  hipMemsetAsync(d_ws, 0, 5888 * sizeof(float), stream);  // accumulators -> 0

  const int nchunks = N / CHUNK_ROWS;  // 4194304/128 = 32768
  float invN = 1.0f / (float)N;

  pass1<<<4096, 128, 0, stream>>>((const float4*)probs, (const float4*)y,
                                  (float2*)us, uminInvSlots, umaxSlots,
                                  ceSlots, focalSlots, nchunks);
  pass2<<<1024, 256, 0, stream>>>((const float4*)us, N / 4, uminInvSlots,
                                  umaxSlots, ghist);
  pass3<<<1, 256, 0, stream>>>(ghist, ceSlots, focalSlots, out, invN);
}